// Round 1
// baseline (361.203 us; speedup 1.0000x reference)
//
#include <hip/hip_runtime.h>

// CLM_26594437496868: co-attention (dual-softmax) + conv3x3 + BN + LeakyReLU
// b=4, c=64, h=w=64, hw=4096.
//
// Pipeline:
//   1. prep:  exl = W_lin @ ex (fp32), emit bf16 copies in [pos][ch] (exlT,qT)
//             and [ch][pos] (q_bf, ex_bf) layouts.
//   2. attn:  two flash-attention passes (pass0: Q=exlT,K=qT,V=q_bf -> O1;
//             pass1: Q=qT,K=exlT,V=ex_bf -> O2), 16x16x32 bf16 MFMA,
//             online softmax, P via XOR-swizzled per-wave LDS.
//   3. conv:  x = O1+O2+ex+q; 3x3 conv, y to ws + per-channel sum/sumsq atomics.
//   4. bn:    normalize with batch stats, gamma/beta, leaky relu -> d_out.

typedef short bf16x8 __attribute__((ext_vector_type(8)));
typedef float f32x4 __attribute__((ext_vector_type(4)));
typedef unsigned short ushort_t;
typedef ushort_t ushort8 __attribute__((ext_vector_type(8)));

#define HW 4096
#define NC 64
#define NB 4
#define L2E 1.44269504f

__device__ __forceinline__ ushort_t f2bf(float f) {
  unsigned u = __builtin_bit_cast(unsigned, f);
  unsigned r = u + 0x7FFFu + ((u >> 16) & 1u);
  return (ushort_t)(r >> 16);
}

// ---------------------------------------------------------------- prep ----
__global__ __launch_bounds__(256) void prep_kernel(
    const float* __restrict__ ex, const float* __restrict__ q,
    const float* __restrict__ Wl,
    ushort_t* __restrict__ exlT, ushort_t* __restrict__ qT,
    ushort_t* __restrict__ q_bf, ushort_t* __restrict__ ex_bf)
{
  __shared__ float xls[64][256];
  const int t = threadIdx.x;
  const int b = blockIdx.x >> 4;
  const int pos = ((blockIdx.x & 15) << 8) + t;

  const float* exb = ex + (size_t)b * NC * HW;
  const float* qb  = q  + (size_t)b * NC * HW;
  ushort_t* exlTb = exlT + (size_t)b * HW * NC;
  ushort_t* qTb   = qT   + (size_t)b * HW * NC;
  ushort_t* qbfb  = q_bf + (size_t)b * NC * HW;
  ushort_t* exbfb = ex_bf+ (size_t)b * NC * HW;

  // query: cast to bf16 in [ch][pos] and transpose to [pos][ch]
  for (int g = 0; g < 4; ++g) {
    ushort8 h0, h1;
#pragma unroll
    for (int j = 0; j < 8; ++j) {
      float v = qb[(g * 16 + j) * HW + pos];
      ushort_t hv = f2bf(v);
      qbfb[(g * 16 + j) * HW + pos] = hv;
      h0[j] = hv;
    }
#pragma unroll
    for (int j = 8; j < 16; ++j) {
      float v = qb[(g * 16 + j) * HW + pos];
      ushort_t hv = f2bf(v);
      qbfb[(g * 16 + j) * HW + pos] = hv;
      h1[j - 8] = hv;
    }
    *(ushort8*)(qTb + (size_t)pos * NC + g * 16)     = h0;
    *(ushort8*)(qTb + (size_t)pos * NC + g * 16 + 8) = h1;
  }

  // exemplar: stage fp32 column in LDS (own column only -> no barrier), cast
  for (int c = 0; c < 64; ++c) {
    float v = exb[c * HW + pos];
    xls[c][t] = v;
    exbfb[c * HW + pos] = f2bf(v);
  }

  // exl[o] = sum_c W_lin[o][c] * ex[c][pos]; write bf16 [pos][ch]
  for (int og = 0; og < 4; ++og) {
    float acc[16];
#pragma unroll
    for (int oo = 0; oo < 16; ++oo) acc[oo] = 0.f;
    for (int c = 0; c < 64; ++c) {
      float xv = xls[c][t];
#pragma unroll
      for (int oo = 0; oo < 16; ++oo)
        acc[oo] += Wl[(og * 16 + oo) * 64 + c] * xv;
    }
    ushort8 h0, h1;
#pragma unroll
    for (int oo = 0; oo < 8; ++oo) h0[oo] = f2bf(acc[oo]);
#pragma unroll
    for (int oo = 0; oo < 8; ++oo) h1[oo] = f2bf(acc[oo + 8]);
    *(ushort8*)(exlTb + (size_t)pos * NC + og * 16)     = h0;
    *(ushort8*)(exlTb + (size_t)pos * NC + og * 16 + 8) = h1;
  }
}

// ---------------------------------------------------------------- attn ----
// grid: 512 = 2 passes x 4 batches x 64 q-blocks(64 rows). 4 waves/block,
// 16 q-rows per wave. MFMA 16x16x32 bf16.
// A-frag (Q): lane: row=l&15, k=(l>>4)*8+i  -> contiguous in [pos][ch].
// B-frag (K^T): lane: kvcol=l&15, k(ch)=(l>>4)*8+i -> contiguous in [pos][ch].
// B-frag (V): lane: ch=l&15, k(kv)=(l>>4)*8+i -> contiguous in [ch][pos].
// P (D-layout: row=(l>>4)*4+r, col=16t+(l&15)) -> LDS (XOR swizzle
// byte^=(row&7)<<4) -> reread as A-frag for PV.
__global__ __launch_bounds__(256) void attn_kernel(
    const ushort_t* __restrict__ exlT, const ushort_t* __restrict__ qT,
    const ushort_t* __restrict__ q_bf, const ushort_t* __restrict__ ex_bf,
    float* __restrict__ O1, float* __restrict__ O2)
{
  __shared__ ushort_t P_lds[4][1024];  // per-wave 16x64 bf16, swizzled

  const int gid  = blockIdx.x;
  const int pass = gid >> 8;
  const int b    = (gid >> 6) & 3;
  const int qb   = gid & 63;
  const int w    = threadIdx.x >> 6;
  const int lane = threadIdx.x & 63;
  const int lr = lane & 15, lg = lane >> 4;
  const int qrow0 = qb * 64 + w * 16;

  const ushort_t* QT = (pass ? qT : exlT) + (size_t)b * HW * NC;
  const ushort_t* KT = (pass ? exlT : qT) + (size_t)b * HW * NC;
  const ushort_t* V  = (pass ? ex_bf : q_bf) + (size_t)b * NC * HW;
  float* Ob = (pass ? O2 : O1) + (size_t)b * HW * NC;

  bf16x8 aq[2];
  {
    const ushort_t* qp = QT + (size_t)(qrow0 + lr) * NC + lg * 8;
    aq[0] = *(const bf16x8*)(qp);
    aq[1] = *(const bf16x8*)(qp + 32);
  }

  f32x4 O[4];
  float m[4], l[4];
#pragma unroll
  for (int t = 0; t < 4; ++t) O[t] = (f32x4){0.f, 0.f, 0.f, 0.f};
#pragma unroll
  for (int r = 0; r < 4; ++r) { m[r] = -3.0e38f; l[r] = 0.f; }

  ushort_t* Pw = P_lds[w];

  for (int kv = 0; kv < 64; ++kv) {
    const int kvbase = kv * 64;

    // S = Q K^T  (16 rows x 64 kv)
    f32x4 s[4];
#pragma unroll
    for (int t = 0; t < 4; ++t) s[t] = (f32x4){0.f, 0.f, 0.f, 0.f};
#pragma unroll
    for (int ks = 0; ks < 2; ++ks) {
#pragma unroll
      for (int t = 0; t < 4; ++t) {
        bf16x8 kf = *(const bf16x8*)(KT + (size_t)(kvbase + t * 16 + lr) * NC
                                     + ks * 32 + lg * 8);
        s[t] = __builtin_amdgcn_mfma_f32_16x16x32_bf16(aq[ks], kf, s[t], 0, 0, 0);
      }
    }

    // online softmax over kv (row = lg*4+r, col = 16t+lr)
    float mx[4];
#pragma unroll
    for (int r = 0; r < 4; ++r) {
      float v = fmaxf(fmaxf(s[0][r], s[1][r]), fmaxf(s[2][r], s[3][r]));
      v = fmaxf(v, __shfl_xor(v, 1));
      v = fmaxf(v, __shfl_xor(v, 2));
      v = fmaxf(v, __shfl_xor(v, 4));
      v = fmaxf(v, __shfl_xor(v, 8));
      mx[r] = v;
    }
#pragma unroll
    for (int r = 0; r < 4; ++r) {
      float mn = fmaxf(m[r], mx[r]);
      float scale = exp2f((m[r] - mn) * L2E);
      m[r] = mn;
      const int row = lg * 4 + r;
      const int rowswz = (row & 7) << 4;
      float ps = 0.f;
#pragma unroll
      for (int t = 0; t < 4; ++t) {
        float p = exp2f((s[t][r] - mn) * L2E);
        ps += p;
        unsigned pu = __builtin_bit_cast(unsigned, p);
        int byte = ((row << 7) + ((t * 16 + lr) << 1)) ^ rowswz;
        *(ushort_t*)((char*)Pw + byte) = (ushort_t)(pu >> 16);
      }
      ps += __shfl_xor(ps, 1);
      ps += __shfl_xor(ps, 2);
      ps += __shfl_xor(ps, 4);
      ps += __shfl_xor(ps, 8);
      l[r] = l[r] * scale + ps;
      O[0][r] *= scale; O[1][r] *= scale; O[2][r] *= scale; O[3][r] *= scale;
    }

    // O += P V
#pragma unroll
    for (int ks = 0; ks < 2; ++ks) {
      int byte0 = ((lr << 7) + ks * 64 + lg * 16) ^ ((lr & 7) << 4);
      bf16x8 pa = *(const bf16x8*)((char*)Pw + byte0);
#pragma unroll
      for (int t = 0; t < 4; ++t) {
        bf16x8 vf = *(const bf16x8*)(V + (size_t)(t * 16 + lr) * HW
                                     + kvbase + ks * 32 + lg * 8);
        O[t] = __builtin_amdgcn_mfma_f32_16x16x32_bf16(pa, vf, O[t], 0, 0, 0);
      }
    }
  }

  float inv[4];
#pragma unroll
  for (int r = 0; r < 4; ++r) inv[r] = 1.f / l[r];
#pragma unroll
  for (int t = 0; t < 4; ++t)
#pragma unroll
    for (int r = 0; r < 4; ++r)
      Ob[(size_t)(qrow0 + lg * 4 + r) * NC + t * 16 + lr] = O[t][r] * inv[r];
}

// ---------------------------------------------------------------- conv ----
// grid: 256 = 4 b x 64 h rows. LDS holds x[c][3 rows][w+halo] fp32.
__global__ __launch_bounds__(256) void conv_kernel(
    const float* __restrict__ exF, const float* __restrict__ qF,
    const float* __restrict__ O1, const float* __restrict__ O2,
    const float* __restrict__ Wc,
    float* __restrict__ y, float* __restrict__ stats)
{
  __shared__ float xls[64][3][67];
  const int t = threadIdx.x;
  const int b = blockIdx.x >> 6;
  const int h = blockIdx.x & 63;

  const float* exb = exF + (size_t)b * NC * HW;
  const float* qb  = qF  + (size_t)b * NC * HW;
  const float* O1b = O1 + (size_t)b * HW * NC;
  const float* O2b = O2 + (size_t)b * HW * NC;

  // stage ex+q (zero for out-of-range rows); mapping: 4 ch x 64 w per iter
#pragma unroll
  for (int ky = 0; ky < 3; ++ky) {
    int hs = h + ky - 1;
    bool valid = (hs >= 0) && (hs < 64);
    for (int it = 0; it < 16; ++it) {
      int c  = it * 4 + (t >> 6);
      int wx = t & 63;
      float v = 0.f;
      if (valid) v = exb[c * HW + hs * 64 + wx] + qb[c * HW + hs * 64 + wx];
      xls[c][ky][wx + 1] = v;
    }
  }
  if (t < 192) { int c = t & 63; int ky = t >> 6; xls[c][ky][0] = 0.f; xls[c][ky][65] = 0.f; }
  __syncthreads();

  // add O1+O2 ([pos][ch] layout); mapping: 4 w x 64 ch per iter
#pragma unroll
  for (int ky = 0; ky < 3; ++ky) {
    int hs = h + ky - 1;
    if (hs >= 0 && hs < 64) {
      for (int it = 0; it < 16; ++it) {
        int wx = it * 4 + (t >> 6);
        int c  = t & 63;
        size_t off = (size_t)(hs * 64 + wx) * NC + c;
        xls[c][ky][wx + 1] += O1b[off] + O2b[off];
      }
    }
  }
  __syncthreads();

  const int o   = t >> 2;
  const int ws0 = (t & 3) * 16;
  float acc[16];
#pragma unroll
  for (int i = 0; i < 16; ++i) acc[i] = 0.f;

  for (int c = 0; c < 64; ++c) {
#pragma unroll
    for (int ky = 0; ky < 3; ++ky) {
      const float* wp = Wc + ((o * 64 + c) * 3 + ky) * 3;
      float w0 = wp[0], w1 = wp[1], w2 = wp[2];
      const float* xr = &xls[c][ky][ws0];
      float r[18];
#pragma unroll
      for (int i = 0; i < 18; ++i) r[i] = xr[i];
#pragma unroll
      for (int i = 0; i < 16; ++i)
        acc[i] += r[i] * w0 + r[i + 1] * w1 + r[i + 2] * w2;
    }
  }

  float s1 = 0.f, s2 = 0.f;
#pragma unroll
  for (int i = 0; i < 16; ++i) { s1 += acc[i]; s2 += acc[i] * acc[i]; }
  float* yb = y + (size_t)(b * 64 + o) * HW + h * 64 + ws0;
#pragma unroll
  for (int i = 0; i < 16; ++i) yb[i] = acc[i];

  s1 += __shfl_xor(s1, 1); s1 += __shfl_xor(s1, 2);
  s2 += __shfl_xor(s2, 1); s2 += __shfl_xor(s2, 2);
  if ((t & 3) == 0) { atomicAdd(&stats[o], s1); atomicAdd(&stats[64 + o], s2); }
}

// ------------------------------------------------------------------ bn ----
__global__ __launch_bounds__(256) void bn_kernel(
    const float* __restrict__ y, const float* __restrict__ stats,
    const float* __restrict__ gamma, const float* __restrict__ beta,
    float* __restrict__ out)
{
  const int e = (blockIdx.x * 256 + threadIdx.x) * 4;
  const int o = (e >> 12) & 63;
  float mean = stats[o] * (1.f / 16384.f);
  float var  = stats[64 + o] * (1.f / 16384.f) - mean * mean;
  float g  = gamma[o] * rsqrtf(var + 1e-5f);
  float bt = beta[o] - mean * g;
  float4 v = *(const float4*)(y + e);
  float4 r;
  r.x = v.x * g + bt; r.x = r.x > 0.f ? r.x : 0.1f * r.x;
  r.y = v.y * g + bt; r.y = r.y > 0.f ? r.y : 0.1f * r.y;
  r.z = v.z * g + bt; r.z = r.z > 0.f ? r.z : 0.1f * r.z;
  r.w = v.w * g + bt; r.w = r.w > 0.f ? r.w : 0.1f * r.w;
  *(float4*)(out + e) = r;
}

// -------------------------------------------------------------- launch ----
extern "C" void kernel_launch(void* const* d_in, const int* in_sizes, int n_in,
                              void* d_out, int out_size, void* d_ws, size_t ws_size,
                              hipStream_t stream)
{
  const float* ex    = (const float*)d_in[0];
  const float* q     = (const float*)d_in[1];
  const float* Wl    = (const float*)d_in[2];
  const float* Wc    = (const float*)d_in[3];
  const float* gamma = (const float*)d_in[4];
  const float* beta  = (const float*)d_in[5];
  float* out = (float*)d_out;

  char* ws = (char*)d_ws;
  ushort_t* exlT  = (ushort_t*)(ws);                 // 2 MB  bf16 [b][pos][ch]
  ushort_t* qT    = (ushort_t*)(ws + (2u << 20));    // 2 MB  bf16 [b][pos][ch]
  ushort_t* q_bf  = (ushort_t*)(ws + (4u << 20));    // 2 MB  bf16 [b][ch][pos]
  ushort_t* ex_bf = (ushort_t*)(ws + (6u << 20));    // 2 MB  bf16 [b][ch][pos]
  float* O1    = (float*)(ws + (8u << 20));          // 4 MB  f32 [b][pos][ch]
  float* O2    = (float*)(ws + (12u << 20));         // 4 MB  f32 [b][pos][ch]
  float* yBuf  = (float*)(ws + (16u << 20));         // 4 MB  f32 [b][o][pos]
  float* stats = (float*)(ws + (20u << 20));         // 512 B

  hipMemsetAsync(stats, 0, 128 * sizeof(float), stream);
  prep_kernel<<<64, 256, 0, stream>>>(ex, q, Wl, exlT, qT, q_bf, ex_bf);
  attn_kernel<<<512, 256, 0, stream>>>(exlT, qT, q_bf, ex_bf, O1, O2);
  conv_kernel<<<256, 256, 0, stream>>>(ex, q, O1, O2, Wc, yBuf, stats);
  bn_kernel<<<1024, 256, 0, stream>>>(yBuf, stats, gamma, beta, out);
}